// Round 3
// baseline (93.874 us; speedup 1.0000x reference)
//
#include <hip/hip_runtime.h>
#include <math.h>

#define NCLUST 32
#define NPTS   1000000
#define LOG2E  1.4426950408889634f
#define TWO_PI 6.2831853071795864f
#define NBLOCKS 1024

// ws layout:
//   float    ws[0] = S accumulator. NOT pre-zeroed: 0xAAAAAAAA as float is
//                    -3.3e-13, negligible vs S ~ O(1e5), so we just add into it.
//   unsigned ws[1] = ticket counter. Initial value is the harness poison
//                    0xAAAAAAAA (deterministic per contract); last block is
//                    ticket - 0xAAAAAAAA == NBLOCKS-1 (or ticket == NBLOCKS-1
//                    if the harness ever zero-inits instead).

__device__ inline void cluster_consts(int t,
                                      const float* __restrict__ means,
                                      const float* __restrict__ chols,
                                      const float* __restrict__ weights,
                                      float& a, float& b, float& c,
                                      float& e, float& f, float& W,
                                      float& L00, float& L10, float& L11,
                                      float& m0, float& m1, float& w) {
    float c00 = chols[t * 4 + 0];
    float c10 = chols[t * 4 + 2];
    float c11 = chols[t * 4 + 3];
    float S00 = fmaf(c00, c00, 1.0f);
    float S10 = c00 * c10;
    float S11 = c10 * c10 + c11 * c11 + 1.0f;
    L00 = sqrtf(S00);
    L10 = S10 / L00;
    L11 = sqrtf(S11 - L10 * L10);
    m0 = means[t * 2 + 0];
    m1 = means[t * 2 + 1];
    w  = weights[t];
    float iL00 = 1.0f / L00;
    float iL11 = 1.0f / L11;
    float Li00 = iL00;
    float Li10 = -L10 * iL00 * iL11;
    float Li11 = iL11;
    const float s = -0.5f * LOG2E;
    a = s * Li00; b = s * Li10; c = s * Li11;
    e = -(2.0f * a * m0 + b * m1);
    f = -(b * m0 + 2.0f * c * m1);
    float g = a * m0 * m0 + b * m0 * m1 + c * m1 * m1;
    float invnorm = 1.0f / (TWO_PI * sqrtf(L00 * L11));
    W = w * invnorm * exp2f(g);
}

__global__ __launch_bounds__(256) void nmsq_fused(const float* __restrict__ X,
                                                  const float* __restrict__ means,
                                                  const float* __restrict__ chols,
                                                  const float* __restrict__ weights,
                                                  float* __restrict__ ws,
                                                  float* __restrict__ out) {
    __shared__ float4 cc[NCLUST * 2];
    __shared__ float sL00[NCLUST], sL10[NCLUST], sL11[NCLUST];
    __shared__ float sM0[NCLUST], sM1[NCLUST], sW[NCLUST];
    __shared__ float red[4];
    __shared__ int sLast;
    const int t = threadIdx.x;

    if (t < NCLUST) {
        float a, b, c, e, f, W, L00, L10, L11, m0, m1, w;
        cluster_consts(t, means, chols, weights, a, b, c, e, f, W,
                       L00, L10, L11, m0, m1, w);
        cc[2 * t]     = make_float4(a, b, c, e);
        cc[2 * t + 1] = make_float4(f, W, 0.0f, 0.0f);
        sL00[t] = L00; sL10[t] = L10; sL11[t] = L11;
        sM0[t] = m0;   sM1[t] = m1;   sW[t] = w;
    }
    __syncthreads();

    const float4* X4 = (const float4*)X;     // 2 points per float4
    const int NV = NPTS / 2;                 // 500000
    const int T = gridDim.x * blockDim.x;

    float acc = 0.0f;
    for (int i = blockIdx.x * blockDim.x + t; i < NV; i += T) {
        float4 p = X4[i];
        float xxA = p.x * p.x, xyA = p.x * p.y, yyA = p.y * p.y;
        float xxB = p.z * p.z, xyB = p.z * p.w, yyB = p.w * p.w;
        float sA = 0.0f, sB = 0.0f;
        #pragma unroll
        for (int k = 0; k < NCLUST; ++k) {
            float4 c0 = cc[2 * k];
            float4 c1 = cc[2 * k + 1];
            float argA = fmaf(c0.x, xxA, fmaf(c0.y, xyA, fmaf(c0.z, yyA,
                         fmaf(c0.w, p.x, c1.x * p.y))));
            float argB = fmaf(c0.x, xxB, fmaf(c0.y, xyB, fmaf(c0.z, yyB,
                         fmaf(c0.w, p.z, c1.x * p.w))));
            sA = fmaf(c1.y, __builtin_amdgcn_exp2f(argA), sA);
            sB = fmaf(c1.y, __builtin_amdgcn_exp2f(argB), sB);
        }
        acc = fmaf(sA, sA, fmaf(sB, sB, acc));
    }

    #pragma unroll
    for (int off = 32; off > 0; off >>= 1) acc += __shfl_down(acc, off, 64);
    int lane = t & 63, wid = t >> 6;
    if (lane == 0) red[wid] = acc;
    __syncthreads();

    if (t == 0) {
        float partial = red[0] + red[1] + red[2] + red[3];
        atomicAdd(&ws[0], partial);             // device-scope (m20)
        __threadfence();                        // order S-add before ticket
        unsigned ticket = atomicAdd((unsigned*)ws + 1, 1u);
        int last = (ticket - 0xAAAAAAAAu == (unsigned)(NBLOCKS - 1)) ||
                   (ticket == (unsigned)(NBLOCKS - 1));
        sLast = last;
    }
    __syncthreads();
    if (!sLast) return;

    // ---- last block only: Z over all 1024 (i,j) pairs + final log ----
    __threadfence();                            // acquire side
    float zp = 0.0f;
    for (int p = t; p < NCLUST * NCLUST; p += 256) {
        int i = p >> 5, j = p & 31;
        float A = sL00[i] + sL00[j];
        float B = sL10[i] + sL10[j];
        float C = sL11[i] + sL11[j];
        float d0 = sM0[i] - sM0[j];
        float d1 = sM1[i] - sM1[j];
        float iA = 1.0f / A, iC = 1.0f / C;
        float qz = d0 * d0 * iA + d1 * d1 * iC - B * d0 * d1 * iA * iC;
        float zt = __builtin_amdgcn_exp2f(-0.5f * LOG2E * qz) / (TWO_PI * sqrtf(A * C));
        zp = fmaf(zt * sW[i], sW[j], zp);
    }
    #pragma unroll
    for (int off = 32; off > 0; off >>= 1) zp += __shfl_down(zp, off, 64);
    __syncthreads();                            // red[] reuse barrier
    if (lane == 0) red[wid] = zp;
    __syncthreads();
    if (t == 0) {
        float Z = red[0] + red[1] + red[2] + red[3];
        float S = atomicAdd(&ws[0], 0.0f);      // read full sum (we were last)
        out[0] = (logf(Z) - logf(S)) * (1.0f / (float)NPTS);
    }
}

extern "C" void kernel_launch(void* const* d_in, const int* in_sizes, int n_in,
                              void* d_out, int out_size, void* d_ws, size_t ws_size,
                              hipStream_t stream) {
    const float* X       = (const float*)d_in[0];
    const float* means   = (const float*)d_in[1];
    const float* chols   = (const float*)d_in[2];
    const float* weights = (const float*)d_in[3];
    // d_in[4] = it (unused)
    float* ws  = (float*)d_ws;
    float* out = (float*)d_out;

    nmsq_fused<<<NBLOCKS, 256, 0, stream>>>(X, means, chols, weights, ws, out);
}

// Round 4
// 83.401 us; speedup vs baseline: 1.1256x; 1.1256x over previous
//
#include <hip/hip_runtime.h>
#include <math.h>

#define NCLUST 32
#define NPTS   1000000
#define LOG2E  1.4426950408889634f
#define TWO_PI 6.2831853071795864f
#define NBLOCKS 1024
#define SLOT_BASE 64   // ws slot offset (in unsigned words) for per-block partials

// Synchronization scheme (no contended atomics — R3 showed ~10ns/RMW serialization
// at the coherence point, +17us tail for 2048 same-address RMWs):
//   - block b: agent-scope RELEASE STORE of its partial (non-negative float,
//     bit31==0) into its OWN slot ws[SLOT_BASE+b]. No contention.
//   - block 0: computes Z, then polls slots with agent-scope ACQUIRE loads.
//     Poison is 0xAAAAAAAA (bit31==1, verified deterministic by R3's pass),
//     so "written" <=> bit31==0. Progress guaranteed: all other blocks are
//     independent and retire, freeing CUs, regardless of block 0 polling.

__device__ inline void cluster_consts(int t,
                                      const float* __restrict__ means,
                                      const float* __restrict__ chols,
                                      const float* __restrict__ weights,
                                      float& a, float& b, float& c,
                                      float& e, float& f, float& W,
                                      float& L00, float& L10, float& L11,
                                      float& m0, float& m1, float& w) {
    float c00 = chols[t * 4 + 0];
    float c10 = chols[t * 4 + 2];
    float c11 = chols[t * 4 + 3];
    float S00 = fmaf(c00, c00, 1.0f);
    float S10 = c00 * c10;
    float S11 = c10 * c10 + c11 * c11 + 1.0f;
    L00 = sqrtf(S00);
    L10 = S10 / L00;
    L11 = sqrtf(S11 - L10 * L10);
    m0 = means[t * 2 + 0];
    m1 = means[t * 2 + 1];
    w  = weights[t];
    float iL00 = 1.0f / L00;
    float iL11 = 1.0f / L11;
    float Li00 = iL00;
    float Li10 = -L10 * iL00 * iL11;
    float Li11 = iL11;
    const float s = -0.5f * LOG2E;
    a = s * Li00; b = s * Li10; c = s * Li11;
    e = -(2.0f * a * m0 + b * m1);
    f = -(b * m0 + 2.0f * c * m1);
    float g = a * m0 * m0 + b * m0 * m1 + c * m1 * m1;
    float invnorm = 1.0f / (TWO_PI * sqrtf(L00 * L11));
    W = w * invnorm * exp2f(g);
}

__global__ __launch_bounds__(256) void nmsq_fused(const float* __restrict__ X,
                                                  const float* __restrict__ means,
                                                  const float* __restrict__ chols,
                                                  const float* __restrict__ weights,
                                                  unsigned* __restrict__ wsu,
                                                  float* __restrict__ out) {
    __shared__ float4 cc[NCLUST * 2];
    __shared__ float sL00[NCLUST], sL10[NCLUST], sL11[NCLUST];
    __shared__ float sM0[NCLUST], sM1[NCLUST], sW[NCLUST];
    __shared__ float red[4], redZ[4], redS[4];
    const int t = threadIdx.x;

    if (t < NCLUST) {
        float a, b, c, e, f, W, L00, L10, L11, m0, m1, w;
        cluster_consts(t, means, chols, weights, a, b, c, e, f, W,
                       L00, L10, L11, m0, m1, w);
        cc[2 * t]     = make_float4(a, b, c, e);
        cc[2 * t + 1] = make_float4(f, W, 0.0f, 0.0f);
        sL00[t] = L00; sL10[t] = L10; sL11[t] = L11;
        sM0[t] = m0;   sM1[t] = m1;   sW[t] = w;
    }
    __syncthreads();

    const float4* X4 = (const float4*)X;     // 2 points per float4
    const int NV = NPTS / 2;                 // 500000
    const int T = gridDim.x * blockDim.x;

    float acc = 0.0f;
    for (int i = blockIdx.x * blockDim.x + t; i < NV; i += T) {
        float4 p = X4[i];
        float xxA = p.x * p.x, xyA = p.x * p.y, yyA = p.y * p.y;
        float xxB = p.z * p.z, xyB = p.z * p.w, yyB = p.w * p.w;
        float sA = 0.0f, sB = 0.0f;
        #pragma unroll
        for (int k = 0; k < NCLUST; ++k) {
            float4 c0 = cc[2 * k];
            float4 c1 = cc[2 * k + 1];
            float argA = fmaf(c0.x, xxA, fmaf(c0.y, xyA, fmaf(c0.z, yyA,
                         fmaf(c0.w, p.x, c1.x * p.y))));
            float argB = fmaf(c0.x, xxB, fmaf(c0.y, xyB, fmaf(c0.z, yyB,
                         fmaf(c0.w, p.z, c1.x * p.w))));
            sA = fmaf(c1.y, __builtin_amdgcn_exp2f(argA), sA);
            sB = fmaf(c1.y, __builtin_amdgcn_exp2f(argB), sB);
        }
        acc = fmaf(sA, sA, fmaf(sB, sB, acc));
    }

    #pragma unroll
    for (int off = 32; off > 0; off >>= 1) acc += __shfl_down(acc, off, 64);
    int lane = t & 63, wid = t >> 6;
    if (lane == 0) red[wid] = acc;
    __syncthreads();

    if (t == 0) {
        float partial = red[0] + red[1] + red[2] + red[3];  // >= 0, bit31 == 0
        __hip_atomic_store(&wsu[SLOT_BASE + blockIdx.x], __float_as_uint(partial),
                           __ATOMIC_RELEASE, __HIP_MEMORY_SCOPE_AGENT);
    }
    if (blockIdx.x != 0) return;

    // ---- block 0 only: Z over 1024 (i,j) pairs (overlaps straggler tails) ----
    float zp = 0.0f;
    for (int p = t; p < NCLUST * NCLUST; p += 256) {
        int i = p >> 5, j = p & 31;
        float A = sL00[i] + sL00[j];
        float B = sL10[i] + sL10[j];
        float C = sL11[i] + sL11[j];
        float d0 = sM0[i] - sM0[j];
        float d1 = sM1[i] - sM1[j];
        float iA = 1.0f / A, iC = 1.0f / C;
        float qz = d0 * d0 * iA + d1 * d1 * iC - B * d0 * d1 * iA * iC;
        float zt = __builtin_amdgcn_exp2f(-0.5f * LOG2E * qz) / (TWO_PI * sqrtf(A * C));
        zp = fmaf(zt * sW[i], sW[j], zp);
    }
    #pragma unroll
    for (int off = 32; off > 0; off >>= 1) zp += __shfl_down(zp, off, 64);
    if (lane == 0) redZ[wid] = zp;

    // ---- poll all 1024 partial slots (4 per thread, uncontended) ----
    float sp = 0.0f;
    for (int i = t; i < NBLOCKS; i += 256) {
        unsigned v;
        do {
            v = __hip_atomic_load(&wsu[SLOT_BASE + i],
                                  __ATOMIC_ACQUIRE, __HIP_MEMORY_SCOPE_AGENT);
        } while (v & 0x80000000u);            // poison has bit31 set; partials don't
        sp += __uint_as_float(v);
    }
    #pragma unroll
    for (int off = 32; off > 0; off >>= 1) sp += __shfl_down(sp, off, 64);
    if (lane == 0) redS[wid] = sp;
    __syncthreads();

    if (t == 0) {
        float Z = redZ[0] + redZ[1] + redZ[2] + redZ[3];
        float S = redS[0] + redS[1] + redS[2] + redS[3];
        out[0] = (logf(Z) - logf(S)) * (1.0f / (float)NPTS);
    }
}

extern "C" void kernel_launch(void* const* d_in, const int* in_sizes, int n_in,
                              void* d_out, int out_size, void* d_ws, size_t ws_size,
                              hipStream_t stream) {
    const float* X       = (const float*)d_in[0];
    const float* means   = (const float*)d_in[1];
    const float* chols   = (const float*)d_in[2];
    const float* weights = (const float*)d_in[3];
    // d_in[4] = it (unused)
    unsigned* wsu = (unsigned*)d_ws;
    float* out = (float*)d_out;

    nmsq_fused<<<NBLOCKS, 256, 0, stream>>>(X, means, chols, weights, wsu, out);
}

// Round 5
// 75.647 us; speedup vs baseline: 1.2410x; 1.1025x over previous
//
#include <hip/hip_runtime.h>
#include <math.h>

#define NCLUST 32
#define NPTS   1000000
#define LOG2E  1.4426950408889634f
#define TWO_PI 6.2831853071795864f
#define NBLOCKS 1024
#define SLOT_BASE 64   // ws slot offset (in unsigned words) for per-block partials

// Sync scheme v3 (R3: contended RMWs cost ~+17us; R4: RELEASE stores emit
// buffer_wbl2 and ACQUIRE polls emit buffer_inv + serialized misses, ~+10us):
//   The ONLY cross-block data is 1024 independent aligned dwords, each
//   self-validating (partial = sum of squares => bit31==0; 0xAA poison has
//   bit31==1, contract verified by R3/R4 passes). A single dword needs
//   atomicity only, NOT ordering:
//   - block b: RELAXED agent-scope atomic store into its OWN slot
//     (performed at the coherence point, no wbl2, no waitcnt drain).
//   - block 0: computes Z first (overlaps stragglers), then polls slots with
//     RELAXED agent-scope atomic loads, 4 independent loads per sweep
//     (vmcnt-pipelined, not serialized spins).
//   Progress: all blocks != 0 are independent and retire regardless.

__device__ inline void cluster_consts(int t,
                                      const float* __restrict__ means,
                                      const float* __restrict__ chols,
                                      const float* __restrict__ weights,
                                      float& a, float& b, float& c,
                                      float& e, float& f, float& W,
                                      float& L00, float& L10, float& L11,
                                      float& m0, float& m1, float& w) {
    float c00 = chols[t * 4 + 0];
    float c10 = chols[t * 4 + 2];
    float c11 = chols[t * 4 + 3];
    float S00 = fmaf(c00, c00, 1.0f);
    float S10 = c00 * c10;
    float S11 = c10 * c10 + c11 * c11 + 1.0f;
    L00 = sqrtf(S00);
    L10 = S10 / L00;
    L11 = sqrtf(S11 - L10 * L10);
    m0 = means[t * 2 + 0];
    m1 = means[t * 2 + 1];
    w  = weights[t];
    float iL00 = 1.0f / L00;
    float iL11 = 1.0f / L11;
    float Li00 = iL00;
    float Li10 = -L10 * iL00 * iL11;
    float Li11 = iL11;
    const float s = -0.5f * LOG2E;
    a = s * Li00; b = s * Li10; c = s * Li11;
    e = -(2.0f * a * m0 + b * m1);
    f = -(b * m0 + 2.0f * c * m1);
    float g = a * m0 * m0 + b * m0 * m1 + c * m1 * m1;
    float invnorm = 1.0f / (TWO_PI * sqrtf(L00 * L11));
    W = w * invnorm * exp2f(g);
}

__global__ __launch_bounds__(256) void nmsq_fused(const float* __restrict__ X,
                                                  const float* __restrict__ means,
                                                  const float* __restrict__ chols,
                                                  const float* __restrict__ weights,
                                                  unsigned* __restrict__ wsu,
                                                  float* __restrict__ out) {
    __shared__ float4 cc[NCLUST * 2];
    __shared__ float sL00[NCLUST], sL10[NCLUST], sL11[NCLUST];
    __shared__ float sM0[NCLUST], sM1[NCLUST], sW[NCLUST];
    __shared__ float red[4], redZ[4], redS[4];
    const int t = threadIdx.x;

    if (t < NCLUST) {
        float a, b, c, e, f, W, L00, L10, L11, m0, m1, w;
        cluster_consts(t, means, chols, weights, a, b, c, e, f, W,
                       L00, L10, L11, m0, m1, w);
        cc[2 * t]     = make_float4(a, b, c, e);
        cc[2 * t + 1] = make_float4(f, W, 0.0f, 0.0f);
        sL00[t] = L00; sL10[t] = L10; sL11[t] = L11;
        sM0[t] = m0;   sM1[t] = m1;   sW[t] = w;
    }
    __syncthreads();

    const float4* X4 = (const float4*)X;     // 2 points per float4
    const int NV = NPTS / 2;                 // 500000
    const int T = gridDim.x * blockDim.x;

    float acc = 0.0f;
    for (int i = blockIdx.x * blockDim.x + t; i < NV; i += T) {
        float4 p = X4[i];
        float xxA = p.x * p.x, xyA = p.x * p.y, yyA = p.y * p.y;
        float xxB = p.z * p.z, xyB = p.z * p.w, yyB = p.w * p.w;
        float sA = 0.0f, sB = 0.0f;
        #pragma unroll
        for (int k = 0; k < NCLUST; ++k) {
            float4 c0 = cc[2 * k];
            float4 c1 = cc[2 * k + 1];
            float argA = fmaf(c0.x, xxA, fmaf(c0.y, xyA, fmaf(c0.z, yyA,
                         fmaf(c0.w, p.x, c1.x * p.y))));
            float argB = fmaf(c0.x, xxB, fmaf(c0.y, xyB, fmaf(c0.z, yyB,
                         fmaf(c0.w, p.z, c1.x * p.w))));
            sA = fmaf(c1.y, __builtin_amdgcn_exp2f(argA), sA);
            sB = fmaf(c1.y, __builtin_amdgcn_exp2f(argB), sB);
        }
        acc = fmaf(sA, sA, fmaf(sB, sB, acc));
    }

    #pragma unroll
    for (int off = 32; off > 0; off >>= 1) acc += __shfl_down(acc, off, 64);
    int lane = t & 63, wid = t >> 6;
    if (lane == 0) red[wid] = acc;
    __syncthreads();

    if (t == 0) {
        float partial = red[0] + red[1] + red[2] + red[3];  // >= 0, bit31 == 0
        __hip_atomic_store(&wsu[SLOT_BASE + blockIdx.x], __float_as_uint(partial),
                           __ATOMIC_RELAXED, __HIP_MEMORY_SCOPE_AGENT);
    }
    if (blockIdx.x != 0) return;

    // ---- block 0 only: Z over 1024 (i,j) pairs (overlaps straggler tails) ----
    float zp = 0.0f;
    for (int p = t; p < NCLUST * NCLUST; p += 256) {
        int i = p >> 5, j = p & 31;
        float A = sL00[i] + sL00[j];
        float B = sL10[i] + sL10[j];
        float C = sL11[i] + sL11[j];
        float d0 = sM0[i] - sM0[j];
        float d1 = sM1[i] - sM1[j];
        float iA = 1.0f / A, iC = 1.0f / C;
        float qz = d0 * d0 * iA + d1 * d1 * iC - B * d0 * d1 * iA * iC;
        float zt = __builtin_amdgcn_exp2f(-0.5f * LOG2E * qz) / (TWO_PI * sqrtf(A * C));
        zp = fmaf(zt * sW[i], sW[j], zp);
    }
    #pragma unroll
    for (int off = 32; off > 0; off >>= 1) zp += __shfl_down(zp, off, 64);
    if (lane == 0) redZ[wid] = zp;

    // ---- poll all 1024 partial slots: 4 pipelined loads per sweep ----
    unsigned v0, v1, v2, v3;
    for (;;) {
        v0 = __hip_atomic_load(&wsu[SLOT_BASE + t + 0 * 256],
                               __ATOMIC_RELAXED, __HIP_MEMORY_SCOPE_AGENT);
        v1 = __hip_atomic_load(&wsu[SLOT_BASE + t + 1 * 256],
                               __ATOMIC_RELAXED, __HIP_MEMORY_SCOPE_AGENT);
        v2 = __hip_atomic_load(&wsu[SLOT_BASE + t + 2 * 256],
                               __ATOMIC_RELAXED, __HIP_MEMORY_SCOPE_AGENT);
        v3 = __hip_atomic_load(&wsu[SLOT_BASE + t + 3 * 256],
                               __ATOMIC_RELAXED, __HIP_MEMORY_SCOPE_AGENT);
        if (!((v0 | v1 | v2 | v3) & 0x80000000u)) break;   // all bit31 clear
    }
    float sp = __uint_as_float(v0) + __uint_as_float(v1) +
               __uint_as_float(v2) + __uint_as_float(v3);
    #pragma unroll
    for (int off = 32; off > 0; off >>= 1) sp += __shfl_down(sp, off, 64);
    if (lane == 0) redS[wid] = sp;
    __syncthreads();

    if (t == 0) {
        float Z = redZ[0] + redZ[1] + redZ[2] + redZ[3];
        float S = redS[0] + redS[1] + redS[2] + redS[3];
        out[0] = (logf(Z) - logf(S)) * (1.0f / (float)NPTS);
    }
}

extern "C" void kernel_launch(void* const* d_in, const int* in_sizes, int n_in,
                              void* d_out, int out_size, void* d_ws, size_t ws_size,
                              hipStream_t stream) {
    const float* X       = (const float*)d_in[0];
    const float* means   = (const float*)d_in[1];
    const float* chols   = (const float*)d_in[2];
    const float* weights = (const float*)d_in[3];
    // d_in[4] = it (unused)
    unsigned* wsu = (unsigned*)d_ws;
    float* out = (float*)d_out;

    nmsq_fused<<<NBLOCKS, 256, 0, stream>>>(X, means, chols, weights, wsu, out);
}